// Round 6
// baseline (100.811 us; speedup 1.0000x reference)
//
#include <hip/hip_runtime.h>

#define BB 32
#define TT 64
#define NN 128
#define FF 128
#define UU 64
#define K1 64
#define K2 32
#define G4 256
#define EPSV 1e-3f
#define SLOPE 0.01f

#define ALD 136   // a row stride in bf16 elems (128 + 8 pad)
#define SLD 136   // sup2T row stride
#define WLD 72    // w2T row stride

typedef __attribute__((ext_vector_type(8))) short short8;
typedef __attribute__((ext_vector_type(4))) float f32x4;

__device__ __forceinline__ float sigmoidf_(float x) {
  return __builtin_amdgcn_rcpf(1.f + __expf(-x));
}
__device__ __forceinline__ float tanhf_(float x) {
  return 1.f - 2.f * __builtin_amdgcn_rcpf(__expf(2.f * x) + 1.f);
}
__device__ __forceinline__ float leaky_(float x) { return x >= 0.f ? x : SLOPE * x; }
__device__ __forceinline__ unsigned short f2bf(float x) {
  union { float f; unsigned u; } v; v.f = x;
  unsigned r = v.u + 0x7fff + ((v.u >> 16) & 1);
  return (unsigned short)(r >> 16);
}

// ---------------- fused prep (blocks 0..31) + xz GEMM (blocks 32..287) ----------------
__global__ __launch_bounds__(256) void k_pre(const float* __restrict__ x,
                                             const float* __restrict__ wk,
                                             const float* __restrict__ bias,
                                             const float* __restrict__ a,
                                             const float* __restrict__ w2,
                                             const float* __restrict__ wr,
                                             float* __restrict__ xz,
                                             float* __restrict__ rsum,
                                             unsigned short* __restrict__ apad,
                                             unsigned short* __restrict__ w2t,
                                             float* __restrict__ wrt) {
  int tid = threadIdx.x;
  if (blockIdx.x < 32) {
    int b = blockIdx.x;
    int wave = tid >> 6, lane = tid & 63;
    const float* ab = a + (size_t)b * NN * NN;
    for (int r = 0; r < 32; ++r) {
      int row = wave * 32 + r;
      float2 v = *(const float2*)(ab + (size_t)row * NN + lane * 2);
      float s = v.x + v.y;
#pragma unroll
      for (int off = 32; off >= 1; off >>= 1) s += __shfl_down(s, off);
      if (lane == 0) rsum[b * NN + row] = s;
    }
    unsigned short* ap = apad + (size_t)b * NN * ALD;
    for (int idx = tid; idx < NN * NN; idx += 256) {
      int i = idx >> 7, j = idx & 127;
      ap[i * ALD + j] = f2bf(ab[idx]);
    }
    if (b == 0) {
      for (int idx = tid; idx < K1 * K2; idx += 256) {
        int k = idx >> 5, m = idx & 31;
        w2t[m * WLD + k] = f2bf(w2[idx]);
      }
    }
    if (b == 1) {
      // transpose lstm_r: wrt[g][v] = wr[v][g]  (coalesced consumption in k_lstm)
      for (int idx = tid; idx < G4 * UU; idx += 256) {
        int gg = idx >> 6, v = idx & 63;
        wrt[idx] = wr[v * G4 + gg];
      }
    }
  } else {
    __shared__ float xs[8][FF];
    int row0 = (blockIdx.x - 32) * 8;
    for (int i = tid; i < 8 * FF; i += 256) xs[i >> 7][i & 127] = x[(size_t)row0 * FF + i];
    __syncthreads();
    int g = tid;
    float acc[8];
    float bg = bias[g];
#pragma unroll
    for (int r = 0; r < 8; ++r) acc[r] = bg;
    for (int f = 0; f < FF; ++f) {
      float w = wk[f * G4 + g];
#pragma unroll
      for (int r = 0; r < 8; ++r) acc[r] += xs[r][f] * w;
    }
#pragma unroll
    for (int r = 0; r < 8; ++r) xz[(size_t)(row0 + r) * G4 + g] = acc[r];
  }
}

// ---------------- LSTM scan: ZERO global ops inside the loop ----------------
// xz[b] fully staged in LDS (64 KB), weights register-resident (coalesced from wrt),
// h history in LDS (16 KB) bulk-written at the end. 1 barrier/step, intra-wave
// gate exchange via 4 shfl. So the per-step vmcnt drain at the barrier is free.
__global__ __launch_bounds__(256, 1) void k_lstm(const float* __restrict__ xz,
                                                 const float* __restrict__ wrt,
                                                 const float* __restrict__ bnl_g,
                                                 const float* __restrict__ bnl_b,
                                                 const float* __restrict__ bnl_m,
                                                 const float* __restrict__ bnl_v,
                                                 float* __restrict__ hbn) {
  __shared__ __align__(16) float xz_lds[TT * G4];   // 64 KB
  __shared__ __align__(16) float hist[TT][UU];      // 16 KB
  __shared__ __align__(16) float hsh[2][UU];        // parity-double-buffered h
  int tid = threadIdx.x;
  int wave = tid >> 6;        // unit-group 0..3
  int lane = tid & 63;
  int q = lane >> 4, up = lane & 15;
  int u = wave * 16 + up;     // this lane's unit
  int g = q * 64 + u;         // this lane's gate column
  int b = blockIdx.x;

  float wcol[UU];
  {
    const float4* wp = (const float4*)(wrt + (size_t)g * UU);
#pragma unroll
    for (int k = 0; k < 16; ++k) ((float4*)wcol)[k] = wp[k];
  }
  {
    const float4* src = (const float4*)(xz + (size_t)b * TT * G4);
    float4* dst = (float4*)xz_lds;
#pragma unroll
    for (int k = 0; k < 16; ++k) dst[tid + k * 256] = src[tid + k * 256];
  }
  float bscale = bnl_g[u] * rsqrtf(bnl_v[u] + EPSV);
  float boff = bnl_b[u] - bnl_m[u] * bscale;
  if (tid < UU) hsh[0][tid] = 0.f;
  float c = 0.f;
  __syncthreads();

  for (int t = 0; t < TT; ++t) {
    const float4* h4 = (const float4*)hsh[t & 1];
    float acc0 = xz_lds[t * G4 + g], acc1 = 0.f, acc2 = 0.f, acc3 = 0.f;
#pragma unroll
    for (int p = 0; p < 16; p += 4) {
      float4 v0 = h4[p], v1 = h4[p + 1], v2 = h4[p + 2], v3 = h4[p + 3];
      acc0 += v0.x * wcol[4 * p + 0] + v0.y * wcol[4 * p + 1] + v0.z * wcol[4 * p + 2] + v0.w * wcol[4 * p + 3];
      acc1 += v1.x * wcol[4 * p + 4] + v1.y * wcol[4 * p + 5] + v1.z * wcol[4 * p + 6] + v1.w * wcol[4 * p + 7];
      acc2 += v2.x * wcol[4 * p + 8] + v2.y * wcol[4 * p + 9] + v2.z * wcol[4 * p + 10] + v2.w * wcol[4 * p + 11];
      acc3 += v3.x * wcol[4 * p + 12] + v3.y * wcol[4 * p + 13] + v3.z * wcol[4 * p + 14] + v3.w * wcol[4 * p + 15];
    }
    float z = (acc0 + acc1) + (acc2 + acc3);
    // unit u's gates live at lanes up+{0,16,32,48}
    float zi = __shfl(z, up);
    float zf = __shfl(z, up + 16);
    float zg = __shfl(z, up + 32);
    float zo = __shfl(z, up + 48);
    float i_ = sigmoidf_(zi), f_ = sigmoidf_(zf), g_ = tanhf_(zg), o_ = sigmoidf_(zo);
    c = f_ * c + i_ * g_;
    float h = o_ * tanhf_(c);
    if (q == 0) {
      hsh[(t & 1) ^ 1][u] = h;
      hist[t][u] = h * bscale + boff;   // LDS, not global
    }
    __syncthreads();   // the only barrier/step; nothing in vmcnt -> free drain
  }
  // bulk coalesced write of the whole history (16 KB)
  const float4* hs4 = (const float4*)&hist[0][0];
  float4* hb4 = (float4*)(hbn + (size_t)b * TT * UU);
#pragma unroll
  for (int k = 0; k < 4; ++k) hb4[tid + k * 256] = hs4[tid + k * 256];
}

// ---------------- fused s1 + GCN1 + GCN2 + d1 partial, one block per (t,b) ----------------
// t-major: 32 concurrent blocks share one 48KB d1w t-slice (L2). Epilogue streams
// d1w coalesced (12 x float4/thread) against a g2 tile staged in LDS (reuses a_lds).
__global__ __launch_bounds__(256) void k_gcn(
    const float* __restrict__ hbn, const float* __restrict__ w1,
    const float* __restrict__ rsum,
    const unsigned short* __restrict__ apad, const unsigned short* __restrict__ w2t,
    const float* __restrict__ b1,
    const float* __restrict__ bn1_g, const float* __restrict__ bn1_b,
    const float* __restrict__ bn1_m, const float* __restrict__ bn1_v,
    const float* __restrict__ b2,
    const float* __restrict__ bn2_g, const float* __restrict__ bn2_b,
    const float* __restrict__ bn2_m, const float* __restrict__ bn2_v,
    const float* __restrict__ d1w, float* __restrict__ part) {
  __shared__ __align__(16) unsigned short a_lds[NN * ALD];  // 34 KB; reused as g2 tile
  __shared__ unsigned short s2_lds[K2 * SLD];
  __shared__ unsigned short w2_lds[K2 * WLD];
  __shared__ float4 gp[K1];
  __shared__ float r_lds[NN];
  __shared__ float p2[3 * K2];
  __shared__ float red[12];

  int blk = blockIdx.x;
  int b = blk & 31, t = blk >> 5;   // t-major
  int tid = threadIdx.x;
  int lane = tid & 63, wave = tid >> 6;
  int l15 = lane & 15, l4 = lane >> 4;

  {
    const uint4* src = (const uint4*)(apad + (size_t)b * NN * ALD);
    uint4* dst = (uint4*)a_lds;
    for (int i = tid; i < NN * ALD / 8; i += 256) dst[i] = src[i];
  }
  {
    const uint2* src = (const uint2*)w2t;
    uint2* dst = (uint2*)w2_lds;
    for (int i = tid; i < K2 * WLD / 4; i += 256) dst[i] = src[i];
  }
  if (tid < K1) {
    float hv = hbn[((size_t)b * TT + t) * UU + tid];
    float s1v = 0.f;
#pragma unroll
    for (int u = 0; u < UU; ++u) s1v += __shfl(hv, u) * w1[u * K1 + tid];
    float s = bn1_g[tid] * rsqrtf(bn1_v[tid] + EPSV);
    gp[tid] = make_float4(s1v, b1[tid], s, bn1_b[tid] - bn1_m[tid] * s);
  }
  if (tid >= 64 && tid < 64 + NN) r_lds[tid - 64] = rsum[b * NN + (tid - 64)];
  if (tid >= 192 && tid < 192 + K2) {
    int m = tid - 192;
    float s = bn2_g[m] * rsqrtf(bn2_v[m] + EPSV);
    p2[m] = b2[m];
    p2[K2 + m] = s;
    p2[2 * K2 + m] = bn2_b[m] - bn2_m[m] * s;
  }
  __syncthreads();

  f32x4 z4 = {0.f, 0.f, 0.f, 0.f};

  // ---- phase 1: g1 frags in-register, MFMA -> sup2, write sup2^T bf16 ----
  {
    float rj0 = r_lds[(wave * 2 + 0) * 16 + l15];
    float rj1 = r_lds[(wave * 2 + 1) * 16 + l15];
    f32x4 acc[2][2];
    acc[0][0] = z4; acc[0][1] = z4; acc[1][0] = z4; acc[1][1] = z4;
#pragma unroll
    for (int kt = 0; kt < 2; ++kt) {
      float4 gpv[8];
#pragma unroll
      for (int e = 0; e < 8; ++e) gpv[e] = gp[kt * 32 + l4 * 8 + e];
      short8 bfrag0 = *((const short8*)&w2_lds[(0 + l15) * WLD + kt * 32 + l4 * 8]);
      short8 bfrag1 = *((const short8*)&w2_lds[(16 + l15) * WLD + kt * 32 + l4 * 8]);
#pragma unroll
      for (int jt = 0; jt < 2; ++jt) {
        float rj = jt ? rj1 : rj0;
        short8 af;
#pragma unroll
        for (int e = 0; e < 8; ++e) {
          float4 p = gpv[e];
          float v = leaky_(rj * p.x + p.y) * p.z + p.w;
          af[e] = (short)f2bf(v);
        }
        acc[jt][0] = __builtin_amdgcn_mfma_f32_16x16x32_bf16(af, bfrag0, acc[jt][0], 0, 0, 0);
        acc[jt][1] = __builtin_amdgcn_mfma_f32_16x16x32_bf16(af, bfrag1, acc[jt][1], 0, 0, 0);
      }
    }
#pragma unroll
    for (int jt = 0; jt < 2; ++jt) {
      int jbase = (wave * 2 + jt) * 16 + l4 * 4;
#pragma unroll
      for (int mt = 0; mt < 2; ++mt) {
        int m = mt * 16 + l15;
        unsigned lo = (unsigned)f2bf(acc[jt][mt][0]) | ((unsigned)f2bf(acc[jt][mt][1]) << 16);
        unsigned hi = (unsigned)f2bf(acc[jt][mt][2]) | ((unsigned)f2bf(acc[jt][mt][3]) << 16);
        uint2 val; val.x = lo; val.y = hi;
        *((uint2*)&s2_lds[m * SLD + jbase]) = val;
      }
    }
  }
  __syncthreads();

  // ---- phase 2: g2 = a @ sup2 (MFMA) ----
  f32x4 acc[2][2];
  acc[0][0] = z4; acc[0][1] = z4; acc[1][0] = z4; acc[1][1] = z4;
#pragma unroll
  for (int kt = 0; kt < 4; ++kt) {
    short8 bfrag0 = *((const short8*)&s2_lds[(0 + l15) * SLD + kt * 32 + l4 * 8]);
    short8 bfrag1 = *((const short8*)&s2_lds[(16 + l15) * SLD + kt * 32 + l4 * 8]);
#pragma unroll
    for (int it = 0; it < 2; ++it) {
      int i = (wave * 2 + it) * 16 + l15;
      short8 afrag = *((const short8*)&a_lds[i * ALD + kt * 32 + l4 * 8]);
      acc[it][0] = __builtin_amdgcn_mfma_f32_16x16x32_bf16(afrag, bfrag0, acc[it][0], 0, 0, 0);
      acc[it][1] = __builtin_amdgcn_mfma_f32_16x16x32_bf16(afrag, bfrag1, acc[it][1], 0, 0, 0);
    }
  }
  __syncthreads();   // all a_lds reads complete; safe to reuse as g2 tile

  // ---- stage g2 (leaky+BN2) into LDS, [128][33] fp32 ----
  float* g2l = (float*)a_lds;
#pragma unroll
  for (int it = 0; it < 2; ++it) {
    int ibase = (wave * 2 + it) * 16 + l4 * 4;
#pragma unroll
    for (int mt = 0; mt < 2; ++mt) {
      int m = mt * 16 + l15;
      float bb = p2[m], bs = p2[K2 + m], bo = p2[2 * K2 + m];
#pragma unroll
      for (int r = 0; r < 4; ++r) {
        g2l[(ibase + r) * 33 + m] = leaky_(acc[it][mt][r] + bb) * bs + bo;
      }
    }
  }
  __syncthreads();

  // ---- d1 dot: stream d1w t-slice coalesced (12 x float4 / thread) ----
  float c0 = 0.f, c1 = 0.f, c2 = 0.f;
  {
    const float4* dw4 = (const float4*)(d1w + (size_t)t * (NN * K2 * 3)) + tid * 12;
    float w[48];
#pragma unroll
    for (int j = 0; j < 12; ++j) {
      float4 v = dw4[j];
      w[4 * j + 0] = v.x; w[4 * j + 1] = v.y; w[4 * j + 2] = v.z; w[4 * j + 3] = v.w;
    }
    int L0 = tid * 16;
#pragma unroll
    for (int k = 0; k < 16; ++k) {
      int L = L0 + k;
      float g2 = g2l[(L >> 5) * 33 + (L & 31)];
      c0 += g2 * w[3 * k + 0];
      c1 += g2 * w[3 * k + 1];
      c2 += g2 * w[3 * k + 2];
    }
  }
#pragma unroll
  for (int off = 32; off >= 1; off >>= 1) {
    c0 += __shfl_down(c0, off);
    c1 += __shfl_down(c1, off);
    c2 += __shfl_down(c2, off);
  }
  if (lane == 0) { red[wave * 3 + 0] = c0; red[wave * 3 + 1] = c1; red[wave * 3 + 2] = c2; }
  __syncthreads();
  if (tid == 0) {
    float s0 = 0.f, s1v = 0.f, s2v = 0.f;
    for (int w = 0; w < 4; ++w) { s0 += red[w * 3]; s1v += red[w * 3 + 1]; s2v += red[w * 3 + 2]; }
    part[((size_t)b * TT + t) * 3 + 0] = s0;
    part[((size_t)b * TT + t) * 3 + 1] = s1v;
    part[((size_t)b * TT + t) * 3 + 2] = s2v;
  }
}

// ---------------- final: reduce partials over t, relu, d2 ----------------
__global__ __launch_bounds__(128) void k_out(const float* __restrict__ part,
                                             const float* __restrict__ d1b,
                                             const float* __restrict__ d2w,
                                             const float* __restrict__ d2b,
                                             float* __restrict__ out) {
  int b = blockIdx.x, n = threadIdx.x;
  float s[3] = {0.f, 0.f, 0.f};
  const float* p = part + (size_t)b * TT * 3;
  for (int t = 0; t < TT; ++t) {
    s[0] += p[t * 3];
    s[1] += p[t * 3 + 1];
    s[2] += p[t * 3 + 2];
  }
  float o = d2b[n];
#pragma unroll
  for (int c = 0; c < 3; ++c) {
    float d = s[c] + d1b[c];
    d = d > 0.f ? d : 0.f;
    o += d * d2w[c * NN + n];
  }
  out[b * NN + n] = o;
}

extern "C" void kernel_launch(void* const* d_in, const int* in_sizes, int n_in,
                              void* d_out, int out_size, void* d_ws, size_t ws_size,
                              hipStream_t stream) {
  const float* x      = (const float*)d_in[0];
  const float* a      = (const float*)d_in[1];
  const float* lstm_k = (const float*)d_in[2];
  const float* lstm_r = (const float*)d_in[3];
  const float* lstm_b = (const float*)d_in[4];
  const float* bnl_g  = (const float*)d_in[5];
  const float* bnl_b  = (const float*)d_in[6];
  const float* bnl_m  = (const float*)d_in[7];
  const float* bnl_v  = (const float*)d_in[8];
  const float* w1     = (const float*)d_in[9];
  const float* b1     = (const float*)d_in[10];
  const float* bn1_g  = (const float*)d_in[11];
  const float* bn1_b  = (const float*)d_in[12];
  const float* bn1_m  = (const float*)d_in[13];
  const float* bn1_v  = (const float*)d_in[14];
  const float* w2     = (const float*)d_in[15];
  const float* b2     = (const float*)d_in[16];
  const float* bn2_g  = (const float*)d_in[17];
  const float* bn2_b  = (const float*)d_in[18];
  const float* bn2_m  = (const float*)d_in[19];
  const float* bn2_v  = (const float*)d_in[20];
  const float* d1_w   = (const float*)d_in[21];
  const float* d1_b   = (const float*)d_in[22];
  const float* d2_w   = (const float*)d_in[23];
  const float* d2_b   = (const float*)d_in[24];
  float* out = (float*)d_out;

  char* ws = (char*)d_ws;
  float* xz            = (float*)(ws + 0);                 // 2,097,152 B
  float* hbn           = (float*)(ws + 2097152);           //   524,288 B
  float* rsum          = (float*)(ws + 2621440);           //    16,384 B
  float* part          = (float*)(ws + 2637824);           //    24,576 B
  unsigned short* apad = (unsigned short*)(ws + 2662400);  // 1,114,112 B
  unsigned short* w2t  = (unsigned short*)(ws + 3776512);  //     4,608 B
  float* wrt           = (float*)(ws + 3781120);           //    65,536 B

  k_pre<<<32 + BB * TT / 8, 256, 0, stream>>>(x, lstm_k, lstm_b, a, w2, lstm_r,
                                              xz, rsum, apad, w2t, wrt);
  k_lstm<<<BB, 256, 0, stream>>>(xz, wrt, bnl_g, bnl_b, bnl_m, bnl_v, hbn);
  k_gcn<<<BB * TT, 256, 0, stream>>>(hbn, w1, rsum, apad, w2t, b1, bn1_g, bn1_b, bn1_m, bn1_v,
                                     b2, bn2_g, bn2_b, bn2_m, bn2_v, d1_w, part);
  k_out<<<BB, 128, 0, stream>>>(part, d1_b, d2_w, d2_b, out);
}

// Round 7
// 80.311 us; speedup vs baseline: 1.2553x; 1.2553x over previous
//
#include <hip/hip_runtime.h>

#define BB 32
#define TT 64
#define NN 128
#define FF 128
#define UU 64
#define K1 64
#define K2 32
#define G4 256
#define EPSV 1e-3f
#define SLOPE 0.01f

#define ALD 136   // a row stride in bf16 elems (128 + 8 pad)
#define SLD 136   // sup2T row stride
#define WLD 72    // w2T row stride

typedef __attribute__((ext_vector_type(8))) short short8;
typedef __attribute__((ext_vector_type(4))) float f32x4;
typedef __attribute__((ext_vector_type(2))) __fp16 half2v;

__device__ __forceinline__ float sigmoidf_(float x) {
  return __builtin_amdgcn_rcpf(1.f + __expf(-x));
}
__device__ __forceinline__ float tanhf_(float x) {
  return 1.f - 2.f * __builtin_amdgcn_rcpf(__expf(2.f * x) + 1.f);
}
__device__ __forceinline__ float leaky_(float x) { return x >= 0.f ? x : SLOPE * x; }
__device__ __forceinline__ unsigned short f2bf(float x) {
  union { float f; unsigned u; } v; v.f = x;
  unsigned r = v.u + 0x7fff + ((v.u >> 16) & 1);
  return (unsigned short)(r >> 16);
}

// ---------------- fused prep (blocks 0..31) + xz GEMM (blocks 32..287) ----------------
__global__ __launch_bounds__(256) void k_pre(const float* __restrict__ x,
                                             const float* __restrict__ wk,
                                             const float* __restrict__ bias,
                                             const float* __restrict__ a,
                                             const float* __restrict__ w2,
                                             const float* __restrict__ wr,
                                             float* __restrict__ xz,
                                             float* __restrict__ rsum,
                                             unsigned short* __restrict__ apad,
                                             unsigned short* __restrict__ w2t,
                                             unsigned* __restrict__ wrp) {
  int tid = threadIdx.x;
  if (blockIdx.x < 32) {
    int b = blockIdx.x;
    int wave = tid >> 6, lane = tid & 63;
    const float* ab = a + (size_t)b * NN * NN;
    for (int r = 0; r < 32; ++r) {
      int row = wave * 32 + r;
      float2 v = *(const float2*)(ab + (size_t)row * NN + lane * 2);
      float s = v.x + v.y;
#pragma unroll
      for (int off = 32; off >= 1; off >>= 1) s += __shfl_down(s, off);
      if (lane == 0) rsum[b * NN + row] = s;
    }
    unsigned short* ap = apad + (size_t)b * NN * ALD;
    for (int idx = tid; idx < NN * NN; idx += 256) {
      int i = idx >> 7, j = idx & 127;
      ap[i * ALD + j] = f2bf(ab[idx]);
    }
    if (b == 0) {
      for (int idx = tid; idx < K1 * K2; idx += 256) {
        int k = idx >> 5, m = idx & 31;
        w2t[m * WLD + k] = f2bf(w2[idx]);
      }
    }
    if (b == 1) {
      // pack Wr as f16x2 pairs: wrp[gate][p][u] = half2(wr[2p][gate*64+u], wr[2p+1][gate*64+u])
      for (int idx = tid; idx < 4 * 32 * UU; idx += 256) {
        int u2 = idx & 63;
        int p = (idx >> 6) & 31;
        int gate = idx >> 11;
        int col = gate * UU + u2;
        union { __fp16 h[2]; unsigned u; } pk;
        pk.h[0] = (__fp16)wr[(2 * p) * G4 + col];
        pk.h[1] = (__fp16)wr[(2 * p + 1) * G4 + col];
        wrp[idx] = pk.u;
      }
    }
  } else {
    __shared__ float xs[8][FF];
    int row0 = (blockIdx.x - 32) * 8;
    for (int i = tid; i < 8 * FF; i += 256) xs[i >> 7][i & 127] = x[(size_t)row0 * FF + i];
    __syncthreads();
    int g = tid;
    float acc[8];
    float bg = bias[g];
#pragma unroll
    for (int r = 0; r < 8; ++r) acc[r] = bg;
    for (int f = 0; f < FF; ++f) {
      float w = wk[f * G4 + g];
#pragma unroll
      for (int r = 0; r < 8; ++r) acc[r] += xs[r][f] * w;
    }
#pragma unroll
    for (int r = 0; r < 8; ++r) xz[(size_t)(row0 + r) * G4 + g] = acc[r];
  }
}

// ---------------- LSTM scan: ONE WAVE = ONE BATCH, zero barriers ----------------
// lane u owns unit u and computes all 4 of its gates (no cross-lane exchange).
// Weights f16x2-packed, register-resident (128 VGPRs). h exchanged via a 128B
// wave-private LDS buffer: 1 ds_write_b16 + 8 uniform (broadcast) ds_read_b128,
// ordered by lgkmcnt only. In-loop global h store is fire-and-forget.
__global__ __launch_bounds__(64, 1) void k_lstm(const float* __restrict__ xz,
                                                const unsigned* __restrict__ wrp,
                                                const float* __restrict__ bnl_g,
                                                const float* __restrict__ bnl_b,
                                                const float* __restrict__ bnl_m,
                                                const float* __restrict__ bnl_v,
                                                float* __restrict__ hbn) {
  __shared__ __align__(16) float xz_lds[TT * G4];   // 64 KB
  __shared__ __align__(16) __fp16 h16[UU];          // 128 B
  int u = threadIdx.x;   // 64 threads = 1 wave
  int b = blockIdx.x;

  // stage xz[b] into LDS (coalesced float4, one-time)
  {
    const float4* src = (const float4*)(xz + (size_t)b * TT * G4);
    float4* dst = (float4*)xz_lds;
#pragma unroll
    for (int k = 0; k < 64; ++k) dst[u + k * 64] = src[u + k * 64];
  }
  // weights: 4 gate-columns of unit u, f16x2 packed (coalesced loads)
  unsigned wv[4][32];
#pragma unroll
  for (int gate = 0; gate < 4; ++gate)
#pragma unroll
    for (int p = 0; p < 32; ++p) wv[gate][p] = wrp[(gate * 32 + p) * UU + u];

  float bscale = bnl_g[u] * rsqrtf(bnl_v[u] + EPSV);
  float boff = bnl_b[u] - bnl_m[u] * bscale;
  h16[u] = (__fp16)0.f;
  float c = 0.f;
  float* hb = hbn + (size_t)b * TT * UU;

  for (int t = 0; t < TT; ++t) {
    // broadcast-read h (uniform addresses -> no conflicts), unpack statically
    unsigned hw[32];
    {
      const uint4* hq = (const uint4*)h16;
#pragma unroll
      for (int k = 0; k < 8; ++k) {
        uint4 v = hq[k];
        hw[4 * k + 0] = v.x; hw[4 * k + 1] = v.y; hw[4 * k + 2] = v.z; hw[4 * k + 3] = v.w;
      }
    }
    float zi = xz_lds[t * G4 + u];
    float zf = xz_lds[t * G4 + 64 + u];
    float zg = xz_lds[t * G4 + 128 + u];
    float zo = xz_lds[t * G4 + 192 + u];
#pragma unroll
    for (int p = 0; p < 32; ++p) {
      half2v hh = __builtin_bit_cast(half2v, hw[p]);
      zi = __builtin_amdgcn_fdot2(__builtin_bit_cast(half2v, wv[0][p]), hh, zi, false);
      zf = __builtin_amdgcn_fdot2(__builtin_bit_cast(half2v, wv[1][p]), hh, zf, false);
      zg = __builtin_amdgcn_fdot2(__builtin_bit_cast(half2v, wv[2][p]), hh, zg, false);
      zo = __builtin_amdgcn_fdot2(__builtin_bit_cast(half2v, wv[3][p]), hh, zo, false);
    }
    float i_ = sigmoidf_(zi), f_ = sigmoidf_(zf), g_ = tanhf_(zg), o_ = sigmoidf_(zo);
    c = f_ * c + i_ * g_;
    float h = o_ * tanhf_(c);
    h16[u] = (__fp16)h;                 // same-wave LDS, lgkmcnt-ordered
    hb[t * UU + u] = h * bscale + boff; // fire-and-forget (no barrier -> no drain)
  }
}

// ---------------- fused s1 + GCN1 + GCN2 + d1 partial, one block per (t,b) ----------------
__global__ __launch_bounds__(256) void k_gcn(
    const float* __restrict__ hbn, const float* __restrict__ w1,
    const float* __restrict__ rsum,
    const unsigned short* __restrict__ apad, const unsigned short* __restrict__ w2t,
    const float* __restrict__ b1,
    const float* __restrict__ bn1_g, const float* __restrict__ bn1_b,
    const float* __restrict__ bn1_m, const float* __restrict__ bn1_v,
    const float* __restrict__ b2,
    const float* __restrict__ bn2_g, const float* __restrict__ bn2_b,
    const float* __restrict__ bn2_m, const float* __restrict__ bn2_v,
    const float* __restrict__ d1w, float* __restrict__ part) {
  __shared__ unsigned short a_lds[NN * ALD];
  __shared__ unsigned short s2_lds[K2 * SLD];
  __shared__ unsigned short w2_lds[K2 * WLD];
  __shared__ float4 gp[K1];
  __shared__ float r_lds[NN];
  __shared__ float p2[3 * K2];
  __shared__ float red[12];

  int blk = blockIdx.x;
  int b = blk & 31, t = blk >> 5;   // t-major
  int tid = threadIdx.x;
  int lane = tid & 63, wave = tid >> 6;
  int l15 = lane & 15, l4 = lane >> 4;

  {
    const uint4* src = (const uint4*)(apad + (size_t)b * NN * ALD);
    uint4* dst = (uint4*)a_lds;
    for (int i = tid; i < NN * ALD / 8; i += 256) dst[i] = src[i];
  }
  {
    const uint2* src = (const uint2*)w2t;
    uint2* dst = (uint2*)w2_lds;
    for (int i = tid; i < K2 * WLD / 4; i += 256) dst[i] = src[i];
  }
  if (tid < K1) {
    float hv = hbn[((size_t)b * TT + t) * UU + tid];
    float s1v = 0.f;
#pragma unroll
    for (int u = 0; u < UU; ++u) s1v += __shfl(hv, u) * w1[u * K1 + tid];
    float s = bn1_g[tid] * rsqrtf(bn1_v[tid] + EPSV);
    gp[tid] = make_float4(s1v, b1[tid], s, bn1_b[tid] - bn1_m[tid] * s);
  }
  if (tid >= 64 && tid < 64 + NN) r_lds[tid - 64] = rsum[b * NN + (tid - 64)];
  if (tid >= 192 && tid < 192 + K2) {
    int m = tid - 192;
    float s = bn2_g[m] * rsqrtf(bn2_v[m] + EPSV);
    p2[m] = b2[m];
    p2[K2 + m] = s;
    p2[2 * K2 + m] = bn2_b[m] - bn2_m[m] * s;
  }
  __syncthreads();

  f32x4 z4 = {0.f, 0.f, 0.f, 0.f};

  {
    float rj0 = r_lds[(wave * 2 + 0) * 16 + l15];
    float rj1 = r_lds[(wave * 2 + 1) * 16 + l15];
    f32x4 acc[2][2];
    acc[0][0] = z4; acc[0][1] = z4; acc[1][0] = z4; acc[1][1] = z4;
#pragma unroll
    for (int kt = 0; kt < 2; ++kt) {
      float4 gpv[8];
#pragma unroll
      for (int e = 0; e < 8; ++e) gpv[e] = gp[kt * 32 + l4 * 8 + e];
      short8 bfrag0 = *((const short8*)&w2_lds[(0 + l15) * WLD + kt * 32 + l4 * 8]);
      short8 bfrag1 = *((const short8*)&w2_lds[(16 + l15) * WLD + kt * 32 + l4 * 8]);
#pragma unroll
      for (int jt = 0; jt < 2; ++jt) {
        float rj = jt ? rj1 : rj0;
        short8 af;
#pragma unroll
        for (int e = 0; e < 8; ++e) {
          float4 p = gpv[e];
          float v = leaky_(rj * p.x + p.y) * p.z + p.w;
          af[e] = (short)f2bf(v);
        }
        acc[jt][0] = __builtin_amdgcn_mfma_f32_16x16x32_bf16(af, bfrag0, acc[jt][0], 0, 0, 0);
        acc[jt][1] = __builtin_amdgcn_mfma_f32_16x16x32_bf16(af, bfrag1, acc[jt][1], 0, 0, 0);
      }
    }
#pragma unroll
    for (int jt = 0; jt < 2; ++jt) {
      int jbase = (wave * 2 + jt) * 16 + l4 * 4;
#pragma unroll
      for (int mt = 0; mt < 2; ++mt) {
        int m = mt * 16 + l15;
        unsigned lo = (unsigned)f2bf(acc[jt][mt][0]) | ((unsigned)f2bf(acc[jt][mt][1]) << 16);
        unsigned hi = (unsigned)f2bf(acc[jt][mt][2]) | ((unsigned)f2bf(acc[jt][mt][3]) << 16);
        uint2 val; val.x = lo; val.y = hi;
        *((uint2*)&s2_lds[m * SLD + jbase]) = val;
      }
    }
  }
  __syncthreads();

  float c0 = 0.f, c1 = 0.f, c2 = 0.f;
  {
    f32x4 acc[2][2];
    acc[0][0] = z4; acc[0][1] = z4; acc[1][0] = z4; acc[1][1] = z4;
#pragma unroll
    for (int kt = 0; kt < 4; ++kt) {
      short8 bfrag0 = *((const short8*)&s2_lds[(0 + l15) * SLD + kt * 32 + l4 * 8]);
      short8 bfrag1 = *((const short8*)&s2_lds[(16 + l15) * SLD + kt * 32 + l4 * 8]);
#pragma unroll
      for (int it = 0; it < 2; ++it) {
        int i = (wave * 2 + it) * 16 + l15;
        short8 afrag = *((const short8*)&a_lds[i * ALD + kt * 32 + l4 * 8]);
        acc[it][0] = __builtin_amdgcn_mfma_f32_16x16x32_bf16(afrag, bfrag0, acc[it][0], 0, 0, 0);
        acc[it][1] = __builtin_amdgcn_mfma_f32_16x16x32_bf16(afrag, bfrag1, acc[it][1], 0, 0, 0);
      }
    }
    const float* dw = d1w + (size_t)t * NN * K2 * 3;
#pragma unroll
    for (int it = 0; it < 2; ++it) {
      int ibase = (wave * 2 + it) * 16 + l4 * 4;
#pragma unroll
      for (int mt = 0; mt < 2; ++mt) {
        int m = mt * 16 + l15;
        float bb = p2[m], bs = p2[K2 + m], bo = p2[2 * K2 + m];
#pragma unroll
        for (int r = 0; r < 4; ++r) {
          int i = ibase + r;
          float g2 = leaky_(acc[it][mt][r] + bb) * bs + bo;
          const float* dp = dw + ((size_t)i * K2 + m) * 3;
          c0 += g2 * dp[0];
          c1 += g2 * dp[1];
          c2 += g2 * dp[2];
        }
      }
    }
  }
#pragma unroll
  for (int off = 32; off >= 1; off >>= 1) {
    c0 += __shfl_down(c0, off);
    c1 += __shfl_down(c1, off);
    c2 += __shfl_down(c2, off);
  }
  if (lane == 0) { red[wave * 3 + 0] = c0; red[wave * 3 + 1] = c1; red[wave * 3 + 2] = c2; }
  __syncthreads();
  if (tid == 0) {
    float s0 = 0.f, s1v = 0.f, s2v = 0.f;
    for (int w = 0; w < 4; ++w) { s0 += red[w * 3]; s1v += red[w * 3 + 1]; s2v += red[w * 3 + 2]; }
    part[((size_t)b * TT + t) * 3 + 0] = s0;
    part[((size_t)b * TT + t) * 3 + 1] = s1v;
    part[((size_t)b * TT + t) * 3 + 2] = s2v;
  }
}

// ---------------- final: reduce partials over t, relu, d2 ----------------
__global__ __launch_bounds__(128) void k_out(const float* __restrict__ part,
                                             const float* __restrict__ d1b,
                                             const float* __restrict__ d2w,
                                             const float* __restrict__ d2b,
                                             float* __restrict__ out) {
  int b = blockIdx.x, n = threadIdx.x;
  float s[3] = {0.f, 0.f, 0.f};
  const float* p = part + (size_t)b * TT * 3;
  for (int t = 0; t < TT; ++t) {
    s[0] += p[t * 3];
    s[1] += p[t * 3 + 1];
    s[2] += p[t * 3 + 2];
  }
  float o = d2b[n];
#pragma unroll
  for (int c = 0; c < 3; ++c) {
    float d = s[c] + d1b[c];
    d = d > 0.f ? d : 0.f;
    o += d * d2w[c * NN + n];
  }
  out[b * NN + n] = o;
}

extern "C" void kernel_launch(void* const* d_in, const int* in_sizes, int n_in,
                              void* d_out, int out_size, void* d_ws, size_t ws_size,
                              hipStream_t stream) {
  const float* x      = (const float*)d_in[0];
  const float* a      = (const float*)d_in[1];
  const float* lstm_k = (const float*)d_in[2];
  const float* lstm_r = (const float*)d_in[3];
  const float* lstm_b = (const float*)d_in[4];
  const float* bnl_g  = (const float*)d_in[5];
  const float* bnl_b  = (const float*)d_in[6];
  const float* bnl_m  = (const float*)d_in[7];
  const float* bnl_v  = (const float*)d_in[8];
  const float* w1     = (const float*)d_in[9];
  const float* b1     = (const float*)d_in[10];
  const float* bn1_g  = (const float*)d_in[11];
  const float* bn1_b  = (const float*)d_in[12];
  const float* bn1_m  = (const float*)d_in[13];
  const float* bn1_v  = (const float*)d_in[14];
  const float* w2     = (const float*)d_in[15];
  const float* b2     = (const float*)d_in[16];
  const float* bn2_g  = (const float*)d_in[17];
  const float* bn2_b  = (const float*)d_in[18];
  const float* bn2_m  = (const float*)d_in[19];
  const float* bn2_v  = (const float*)d_in[20];
  const float* d1_w   = (const float*)d_in[21];
  const float* d1_b   = (const float*)d_in[22];
  const float* d2_w   = (const float*)d_in[23];
  const float* d2_b   = (const float*)d_in[24];
  float* out = (float*)d_out;

  char* ws = (char*)d_ws;
  float* xz            = (float*)(ws + 0);                 // 2,097,152 B
  float* hbn           = (float*)(ws + 2097152);           //   524,288 B
  float* rsum          = (float*)(ws + 2621440);           //    16,384 B
  float* part          = (float*)(ws + 2637824);           //    24,576 B
  unsigned short* apad = (unsigned short*)(ws + 2662400);  // 1,114,112 B
  unsigned short* w2t  = (unsigned short*)(ws + 3776512);  //     4,608 B
  unsigned* wrp        = (unsigned*)(ws + 3781120);        //    32,768 B

  k_pre<<<32 + BB * TT / 8, 256, 0, stream>>>(x, lstm_k, lstm_b, a, w2, lstm_r,
                                              xz, rsum, apad, w2t, wrp);
  k_lstm<<<BB, 64, 0, stream>>>(xz, wrp, bnl_g, bnl_b, bnl_m, bnl_v, hbn);
  k_gcn<<<BB * TT, 256, 0, stream>>>(hbn, w1, rsum, apad, w2t, b1, bn1_g, bn1_b, bn1_m, bn1_v,
                                     b2, bn2_g, bn2_b, bn2_m, bn2_v, d1_w, part);
  k_out<<<BB, 128, 0, stream>>>(part, d1_b, d2_w, d2_b, out);
}